// Round 1
// baseline (285.964 us; speedup 1.0000x reference)
//
#include <hip/hip_runtime.h>

// Problem constants (match reference)
#define LAMBDA_G 1.938f
#define LAMBDA_F 1.912f
#define TAU_C    3.5f
#define EPSV     1e-8f

constexpr int B = 8, N = 1000, C = 4000, D = 128;

__device__ __forceinline__ float waveReduceSum(float v) {
#pragma unroll
    for (int off = 32; off > 0; off >>= 1)
        v += __shfl_down(v, off, 64);
    return v;
}

__device__ __forceinline__ float waveReduceMax(float v) {
#pragma unroll
    for (int off = 32; off > 0; off >>= 1)
        v = fmaxf(v, __shfl_down(v, off, 64));
    return v;
}

// One block per (b,j). Reads at most ONE 16KB row of the big tensors.
__global__ __launch_bounds__(256) void reward_kernel(
    const float* __restrict__ u_reg, const float* __restrict__ u_food,
    const float* __restrict__ u0,    const float* __restrict__ pop,
    const int*   __restrict__ chosen,
    const float* __restrict__ dd_reg, const float* __restrict__ dd_food,
    const float* __restrict__ fcp,   float* __restrict__ reward)
{
    const int bj = blockIdx.x;
    const int b  = bj / N;
    const int t  = threadIdx.x;
    const int cc = chosen[bj];

    if (cc >= 2) {             // both masks zero -> reward_improve == 0
        if (t == 0) reward[bj] = 0.0f;
        return;
    }

    const float* __restrict__ u    = (cc == 0 ? u_reg : u_food) + (size_t)bj * C;
    const float* __restrict__ u0b  = u0  + (size_t)b * C;
    const float* __restrict__ popb = pop + (size_t)b * C;
    const float  lam = (cc == 0) ? LAMBDA_G : LAMBDA_F;
    const float  dd  = (cc == 0) ? dd_reg[bj] : dd_food[bj];

    float acc = 0.0f;
    const float4* u4  = (const float4*)u;
    const float4* u04 = (const float4*)u0b;
    const float4* p4  = (const float4*)popb;
    for (int c4 = t; c4 < C / 4; c4 += 256) {
        float4 uv = u4[c4];
        float4 ov = u04[c4];
        float4 pv = p4[c4];
        acc += pv.x * uv.x / (ov.x + uv.x + EPSV);
        acc += pv.y * uv.y / (ov.y + uv.y + EPSV);
        acc += pv.z * uv.z / (ov.z + uv.z + EPSV);
        acc += pv.w * uv.w / (ov.w + uv.w + EPSV);
    }

    __shared__ float red[4];
    float ws = waveReduceSum(acc);
    if ((t & 63) == 0) red[t >> 6] = ws;
    __syncthreads();
    if (t == 0) {
        float s       = red[0] + red[1] + red[2] + red[3];
        float revenue = lam * s;
        float delivery = TAU_C * dd * (1.0f / 1000.0f);
        float fixedc   = fcp[bj];
        float adv = revenue * 0.19f - 0.075f * revenue - 0.005f * revenue
                    - delivery - fixedc;
        reward[bj] = fmaxf(adv, 0.0f) * 0.01f;
    }
}

// One block per batch: softmax over N, context = emb^T @ soft, out = ctx @ W^T + bias
__global__ __launch_bounds__(256) void context_kernel(
    const float* __restrict__ reward, const float* __restrict__ emb,
    const float* __restrict__ Wm,     const float* __restrict__ bias,
    float* __restrict__ out)
{
    const int b = blockIdx.x;
    const int t = threadIdx.x;

    __shared__ float e[N];
    __shared__ float red[4];
    __shared__ float ctx[2][D];

    const float* __restrict__ r = reward + b * N;

    // ---- max ----
    float m = -1e30f;
    for (int j = t; j < N; j += 256) m = fmaxf(m, r[j]);
    m = waveReduceMax(m);
    if ((t & 63) == 0) red[t >> 6] = m;
    __syncthreads();
    const float mx = fmaxf(fmaxf(red[0], red[1]), fmaxf(red[2], red[3]));

    // ---- exp + sum ----
    float s = 0.0f;
    for (int j = t; j < N; j += 256) {
        float ev = expf(r[j] - mx);
        e[j] = ev;
        s += ev;
    }
    s = waveReduceSum(s);
    __syncthreads();               // everyone done reading red (and writing e)
    if ((t & 63) == 0) red[t >> 6] = s;
    __syncthreads();
    const float inv = 1.0f / (red[0] + red[1] + red[2] + red[3]);

    // ---- context: threads split j-range in halves, d = t & 127 ----
    const int d    = t & (D - 1);
    const int half = t >> 7;       // 0 or 1
    const float* __restrict__ eb = emb + (size_t)b * N * D;
    float acc = 0.0f;
    const int j0 = half * (N / 2), j1 = j0 + (N / 2);
    for (int j = j0; j < j1; ++j)
        acc += eb[(size_t)j * D + d] * e[j];
    ctx[half][d] = acc;
    __syncthreads();
    if (t < D) ctx[0][t] = (ctx[0][t] + ctx[1][t]) * inv;
    __syncthreads();

    // ---- out[b,i] = sum_d ctx[d] * W[i,d] + bias[i] ----
    if (t < D) {
        const float* __restrict__ wr = Wm + t * D;
        float o = bias[t];
        float a = 0.0f;
#pragma unroll 8
        for (int dd = 0; dd < D; ++dd) a += ctx[0][dd] * wr[dd];
        out[b * D + t] = o + a;
    }
}

extern "C" void kernel_launch(void* const* d_in, const int* in_sizes, int n_in,
                              void* d_out, int out_size, void* d_ws, size_t ws_size,
                              hipStream_t stream) {
    const float* emb     = (const float*)d_in[0];   // [B,N,D]
    const int*   chosen  = (const int*)  d_in[1];   // [B,N]
    const float* u_reg   = (const float*)d_in[2];   // [B,N,C]
    const float* u_food  = (const float*)d_in[3];   // [B,N,C]
    const float* u0      = (const float*)d_in[4];   // [B,C]
    const float* pop     = (const float*)d_in[5];   // [B,C,1]
    const float* dd_reg  = (const float*)d_in[6];   // [B,N,1]
    const float* dd_food = (const float*)d_in[7];   // [B,N,1]
    const float* fcp     = (const float*)d_in[8];   // [B,1,N]
    const float* Wm      = (const float*)d_in[9];   // [D,D]
    const float* bias    = (const float*)d_in[10];  // [D]
    float* out = (float*)d_out;

    float* reward = (float*)d_ws;                   // B*N floats

    reward_kernel<<<B * N, 256, 0, stream>>>(u_reg, u_food, u0, pop, chosen,
                                             dd_reg, dd_food, fcp, reward);
    context_kernel<<<B, 256, 0, stream>>>(reward, emb, Wm, bias, out);
}

// Round 2
// 261.763 us; speedup vs baseline: 1.0925x; 1.0925x over previous
//
#include <hip/hip_runtime.h>

#define LAMBDA_G 1.938f
#define LAMBDA_F 1.912f
#define TAU_C    3.5f
#define EPSV     1e-8f

constexpr int B = 8, N = 1000, C = 4000, D = 128;
constexpr int S = 25, RPB = 40, RPT = 5;   // ctx slabs: 25 slabs x 40 rows; 8 row-groups x 5 rows/thread

__device__ __forceinline__ float waveReduceSum(float v) {
#pragma unroll
    for (int off = 32; off > 0; off >>= 1)
        v += __shfl_down(v, off, 64);
    return v;
}

__device__ __forceinline__ float waveReduceMax(float v) {
#pragma unroll
    for (int off = 32; off > 0; off >>= 1)
        v = fmaxf(v, __shfl_down(v, off, 64));
    return v;
}

// One block per (b,j). Reads at most ONE 16KB row of the big tensors.
__global__ __launch_bounds__(256) void reward_kernel(
    const float* __restrict__ u_reg, const float* __restrict__ u_food,
    const float* __restrict__ u0,    const float* __restrict__ pop,
    const int*   __restrict__ chosen,
    const float* __restrict__ dd_reg, const float* __restrict__ dd_food,
    const float* __restrict__ fcp,   float* __restrict__ reward)
{
    const int bj = blockIdx.x;
    const int b  = bj / N;
    const int t  = threadIdx.x;
    const int cc = chosen[bj];

    if (cc >= 2) {             // both masks zero -> reward_improve == 0
        if (t == 0) reward[bj] = 0.0f;
        return;
    }

    const float* __restrict__ u    = (cc == 0 ? u_reg : u_food) + (size_t)bj * C;
    const float* __restrict__ u0b  = u0  + (size_t)b * C;
    const float* __restrict__ popb = pop + (size_t)b * C;
    const float  lam = (cc == 0) ? LAMBDA_G : LAMBDA_F;
    const float  dd  = (cc == 0) ? dd_reg[bj] : dd_food[bj];

    float acc = 0.0f;
    const float4* u4  = (const float4*)u;
    const float4* u04 = (const float4*)u0b;
    const float4* p4  = (const float4*)popb;
    for (int c4 = t; c4 < C / 4; c4 += 256) {
        float4 uv = u4[c4];
        float4 ov = u04[c4];
        float4 pv = p4[c4];
        acc += pv.x * uv.x / (ov.x + uv.x + EPSV);
        acc += pv.y * uv.y / (ov.y + uv.y + EPSV);
        acc += pv.z * uv.z / (ov.z + uv.z + EPSV);
        acc += pv.w * uv.w / (ov.w + uv.w + EPSV);
    }

    __shared__ float red[4];
    float ws = waveReduceSum(acc);
    if ((t & 63) == 0) red[t >> 6] = ws;
    __syncthreads();
    if (t == 0) {
        float s       = red[0] + red[1] + red[2] + red[3];
        float revenue = lam * s;
        float delivery = TAU_C * dd * (1.0f / 1000.0f);
        float fixedc   = fcp[bj];
        float adv = revenue * 0.19f - 0.075f * revenue - 0.005f * revenue
                    - delivery - fixedc;
        reward[bj] = fmaxf(adv, 0.0f) * 0.01f;
    }
}

// 8 blocks: normalized softmax probs e[b,j] -> ws (reward is L2-resident)
__global__ __launch_bounds__(256) void softmax_kernel(
    const float* __restrict__ reward, float* __restrict__ e_out)
{
    const int b = blockIdx.x;
    const int t = threadIdx.x;

    __shared__ float e[N];
    __shared__ float red[4];

    const float* __restrict__ r = reward + b * N;

    float m = -1e30f;
    for (int j = t; j < N; j += 256) m = fmaxf(m, r[j]);
    m = waveReduceMax(m);
    if ((t & 63) == 0) red[t >> 6] = m;
    __syncthreads();
    const float mx = fmaxf(fmaxf(red[0], red[1]), fmaxf(red[2], red[3]));

    float s = 0.0f;
    for (int j = t; j < N; j += 256) {
        float ev = expf(r[j] - mx);
        e[j] = ev;
        s += ev;
    }
    s = waveReduceSum(s);
    __syncthreads();
    if ((t & 63) == 0) red[t >> 6] = s;
    __syncthreads();
    const float inv = 1.0f / (red[0] + red[1] + red[2] + red[3]);

    for (int j = t; j < N; j += 256)
        e_out[b * N + j] = e[j] * inv;
}

// B*S blocks: partial context over a 40-row slab. float4 loads along D.
__global__ __launch_bounds__(256) void ctx_partial_kernel(
    const float* __restrict__ e, const float* __restrict__ emb,
    float* __restrict__ partials)
{
    const int blk = blockIdx.x;
    const int b = blk / S, s = blk % S;
    const int t = threadIdx.x;
    const int d4 = t & 31;       // which float4 along D (32*4 = 128)
    const int rg = t >> 5;       // row group 0..7

    const float* __restrict__ eb = emb + ((size_t)b * N + s * RPB) * D;
    const float* __restrict__ ev = e + b * N + s * RPB;

    float4 acc = {0.f, 0.f, 0.f, 0.f};
#pragma unroll
    for (int k = 0; k < RPT; ++k) {
        const int j = rg * RPT + k;
        const float w = ev[j];
        const float4 v = ((const float4*)(eb + (size_t)j * D))[d4];
        acc.x += v.x * w; acc.y += v.y * w; acc.z += v.z * w; acc.w += v.w * w;
    }

    __shared__ float lds[8][D];
    *(float4*)&lds[rg][d4 * 4] = acc;
    __syncthreads();
    if (t < D) {
        float sum = 0.f;
#pragma unroll
        for (int g = 0; g < 8; ++g) sum += lds[g][t];
        partials[((size_t)b * S + s) * D + t] = sum;
    }
}

// 8 blocks: reduce S partials -> ctx, then out = ctx @ W^T + bias
__global__ __launch_bounds__(128) void finalize_kernel(
    const float* __restrict__ partials, const float* __restrict__ Wm,
    const float* __restrict__ bias, float* __restrict__ out)
{
    const int b = blockIdx.x;
    const int t = threadIdx.x;

    __shared__ float ctx[D];
    float sum = 0.f;
#pragma unroll 5
    for (int si = 0; si < S; ++si)
        sum += partials[((size_t)b * S + si) * D + t];
    ctx[t] = sum;
    __syncthreads();

    const float* __restrict__ wr = Wm + t * D;
    float a = bias[t];
#pragma unroll 8
    for (int dd = 0; dd < D; ++dd) a += ctx[dd] * wr[dd];
    out[b * D + t] = a;
}

extern "C" void kernel_launch(void* const* d_in, const int* in_sizes, int n_in,
                              void* d_out, int out_size, void* d_ws, size_t ws_size,
                              hipStream_t stream) {
    const float* emb     = (const float*)d_in[0];   // [B,N,D]
    const int*   chosen  = (const int*)  d_in[1];   // [B,N]
    const float* u_reg   = (const float*)d_in[2];   // [B,N,C]
    const float* u_food  = (const float*)d_in[3];   // [B,N,C]
    const float* u0      = (const float*)d_in[4];   // [B,C]
    const float* pop     = (const float*)d_in[5];   // [B,C,1]
    const float* dd_reg  = (const float*)d_in[6];   // [B,N,1]
    const float* dd_food = (const float*)d_in[7];   // [B,N,1]
    const float* fcp     = (const float*)d_in[8];   // [B,1,N]
    const float* Wm      = (const float*)d_in[9];   // [D,D]
    const float* bias    = (const float*)d_in[10];  // [D]
    float* out = (float*)d_out;

    float* reward   = (float*)d_ws;                 // B*N floats
    float* e_probs  = reward + B * N;               // B*N floats
    float* partials = e_probs + B * N;              // B*S*D floats

    reward_kernel<<<B * N, 256, 0, stream>>>(u_reg, u_food, u0, pop, chosen,
                                             dd_reg, dd_food, fcp, reward);
    softmax_kernel<<<B, 256, 0, stream>>>(reward, e_probs);
    ctx_partial_kernel<<<B * S, 256, 0, stream>>>(e_probs, emb, partials);
    finalize_kernel<<<B, 128, 0, stream>>>(partials, Wm, bias, out);
}

// Round 3
// 253.265 us; speedup vs baseline: 1.1291x; 1.0336x over previous
//
#include <hip/hip_runtime.h>

#define LAMBDA_G 1.938f
#define LAMBDA_F 1.912f
#define TAU_C    3.5f
#define EPSV     1e-8f

constexpr int B = 8, N = 1000, C = 4000, D = 128;
constexpr int S = 25, RPB = 40, RPT = 5;   // ctx slabs: 25 slabs x 40 rows; 8 row-groups x 5 rows/thread

typedef float f4 __attribute__((ext_vector_type(4)));

__device__ __forceinline__ float waveReduceSum(float v) {
#pragma unroll
    for (int off = 32; off > 0; off >>= 1)
        v += __shfl_down(v, off, 64);
    return v;
}

// One block per (b,j). Reads at most ONE 16KB row of the big tensors.
// u row is streamed nontemporally (read-once); u0/pop stay L2-hot.
__global__ __launch_bounds__(256) void reward_kernel(
    const float* __restrict__ u_reg, const float* __restrict__ u_food,
    const float* __restrict__ u0,    const float* __restrict__ pop,
    const int*   __restrict__ chosen,
    const float* __restrict__ dd_reg, const float* __restrict__ dd_food,
    const float* __restrict__ fcp,   float* __restrict__ reward)
{
    const int bj = blockIdx.x;
    const int b  = bj / N;
    const int t  = threadIdx.x;
    const int cc = chosen[bj];

    if (cc >= 2) {             // both masks zero -> reward_improve == 0
        if (t == 0) reward[bj] = 0.0f;
        return;
    }

    const float* __restrict__ u    = (cc == 0 ? u_reg : u_food) + (size_t)bj * C;
    const float* __restrict__ u0b  = u0  + (size_t)b * C;
    const float* __restrict__ popb = pop + (size_t)b * C;
    const float  lam = (cc == 0) ? LAMBDA_G : LAMBDA_F;
    const float  dd  = (cc == 0) ? dd_reg[bj] : dd_food[bj];

    float acc = 0.0f;
    const f4* u4  = (const f4*)u;
    const f4* u04 = (const f4*)u0b;
    const f4* p4  = (const f4*)popb;
#pragma unroll
    for (int c4 = t; c4 < C / 4; c4 += 256) {
        f4 uv = __builtin_nontemporal_load(u4 + c4);   // read-once stream
        f4 ov = u04[c4];
        f4 pv = p4[c4];
        acc += pv.x * uv.x / (ov.x + uv.x + EPSV);
        acc += pv.y * uv.y / (ov.y + uv.y + EPSV);
        acc += pv.z * uv.z / (ov.z + uv.z + EPSV);
        acc += pv.w * uv.w / (ov.w + uv.w + EPSV);
    }

    __shared__ float red[4];
    float ws = waveReduceSum(acc);
    if ((t & 63) == 0) red[t >> 6] = ws;
    __syncthreads();
    if (t == 0) {
        float s       = red[0] + red[1] + red[2] + red[3];
        float revenue = lam * s;
        float delivery = TAU_C * dd * (1.0f / 1000.0f);
        float fixedc   = fcp[bj];
        float adv = revenue * 0.19f - 0.075f * revenue - 0.005f * revenue
                    - delivery - fixedc;
        reward[bj] = fmaxf(adv, 0.0f) * 0.01f;
    }
}

// B*S blocks: exp-weighted partial context over a 40-row slab + partial sum(exp).
// reward >= 0 and provably <= ~9, so exp() needs no max-subtraction.
__global__ __launch_bounds__(256) void ctx_partial_kernel(
    const float* __restrict__ reward, const float* __restrict__ emb,
    float* __restrict__ partials, float* __restrict__ psum)
{
    const int blk = blockIdx.x;
    const int b = blk / S, s = blk % S;
    const int t = threadIdx.x;
    const int d4 = t & 31;       // which float4 along D (32*4 = 128)
    const int rg = t >> 5;       // row group 0..7

    const float* __restrict__ eb = emb + ((size_t)b * N + s * RPB) * D;
    const float* __restrict__ rv = reward + b * N + s * RPB;

    __shared__ float esum[RPB];

    f4 acc = {0.f, 0.f, 0.f, 0.f};
#pragma unroll
    for (int k = 0; k < RPT; ++k) {
        const int j = rg * RPT + k;
        const float w = __expf(rv[j]);
        if (d4 == 0) esum[j] = w;
        const f4 v = ((const f4*)(eb + (size_t)j * D))[d4];
        acc += v * w;
    }

    __shared__ float lds[8][D];
    *(f4*)&lds[rg][d4 * 4] = acc;
    __syncthreads();
    if (t < D) {
        float sum = 0.f;
#pragma unroll
        for (int g = 0; g < 8; ++g) sum += lds[g][t];
        partials[((size_t)b * S + s) * D + t] = sum;
    }
    if (t == 0) {
        float se = 0.f;
#pragma unroll
        for (int j = 0; j < RPB; ++j) se += esum[j];
        psum[b * S + s] = se;
    }
}

// 8 blocks: reduce S partials + sumexp -> ctx, then out = ctx @ W^T + bias
__global__ __launch_bounds__(128) void finalize_kernel(
    const float* __restrict__ partials, const float* __restrict__ psum,
    const float* __restrict__ Wm, const float* __restrict__ bias,
    float* __restrict__ out)
{
    const int b = blockIdx.x;
    const int t = threadIdx.x;

    __shared__ float ctx[D];
    float sum = 0.f, se = 0.f;
#pragma unroll 5
    for (int si = 0; si < S; ++si) {
        sum += partials[((size_t)b * S + si) * D + t];
        se  += psum[b * S + si];
    }
    ctx[t] = sum * (1.0f / se);
    __syncthreads();

    const float* __restrict__ wr = Wm + t * D;
    float a = bias[t];
#pragma unroll 8
    for (int dd = 0; dd < D; ++dd) a += ctx[dd] * wr[dd];
    out[b * D + t] = a;
}

extern "C" void kernel_launch(void* const* d_in, const int* in_sizes, int n_in,
                              void* d_out, int out_size, void* d_ws, size_t ws_size,
                              hipStream_t stream) {
    const float* emb     = (const float*)d_in[0];   // [B,N,D]
    const int*   chosen  = (const int*)  d_in[1];   // [B,N]
    const float* u_reg   = (const float*)d_in[2];   // [B,N,C]
    const float* u_food  = (const float*)d_in[3];   // [B,N,C]
    const float* u0      = (const float*)d_in[4];   // [B,C]
    const float* pop     = (const float*)d_in[5];   // [B,C,1]
    const float* dd_reg  = (const float*)d_in[6];   // [B,N,1]
    const float* dd_food = (const float*)d_in[7];   // [B,N,1]
    const float* fcp     = (const float*)d_in[8];   // [B,1,N]
    const float* Wm      = (const float*)d_in[9];   // [D,D]
    const float* bias    = (const float*)d_in[10];  // [D]
    float* out = (float*)d_out;

    float* reward   = (float*)d_ws;                 // B*N
    float* partials = reward + B * N;               // B*S*D
    float* psum     = partials + B * S * D;         // B*S

    reward_kernel<<<B * N, 256, 0, stream>>>(u_reg, u_food, u0, pop, chosen,
                                             dd_reg, dd_food, fcp, reward);
    ctx_partial_kernel<<<B * S, 256, 0, stream>>>(reward, emb, partials, psum);
    finalize_kernel<<<B, 128, 0, stream>>>(partials, psum, Wm, bias, out);
}

// Round 4
// 250.426 us; speedup vs baseline: 1.1419x; 1.0113x over previous
//
#include <hip/hip_runtime.h>

#define LAMBDA_G 1.938f
#define LAMBDA_F 1.912f
#define EPSV     1e-8f

constexpr int B = 8, N = 1000, C = 4000, D = 128;
constexpr int S = 25, RPB = 40, RPT = 5;   // ctx slabs: 25 slabs x 40 rows; 8 row-groups x 5 rows/thread

typedef float f4 __attribute__((ext_vector_type(4)));

__device__ __forceinline__ float waveReduceSum(float v) {
#pragma unroll
    for (int off = 32; off > 0; off >>= 1)
        v += __shfl_down(v, off, 64);
    return v;
}

__device__ __forceinline__ float rcpf(float x) { return __builtin_amdgcn_rcpf(x); }

// One block per PAIR of points (same batch): u0/pop loaded once, applied to
// up to two u-rows. u rows streamed nontemporally (read-once).
__global__ __launch_bounds__(256) void reward_pair_kernel(
    const float* __restrict__ u_reg, const float* __restrict__ u_food,
    const float* __restrict__ u0,    const float* __restrict__ pop,
    const int*   __restrict__ chosen,
    const float* __restrict__ dd_reg, const float* __restrict__ dd_food,
    const float* __restrict__ fcp,   float* __restrict__ reward)
{
    const int blk = blockIdx.x;              // 0 .. B*N/2-1
    const int b   = blk / (N / 2);
    const int bj0 = b * N + (blk % (N / 2)) * 2;
    const int t   = threadIdx.x;

    const int cc0 = chosen[bj0];
    const int cc1 = chosen[bj0 + 1];
    const bool a0 = cc0 < 2, a1 = cc1 < 2;   // block-uniform

    if (!a0 && !a1) {                        // both rewards provably zero
        if (t < 2) reward[bj0 + t] = 0.0f;
        return;
    }

    const f4* __restrict__ u40 = (const f4*)((cc0 == 0 ? u_reg : u_food) + (size_t)bj0 * C);
    const f4* __restrict__ u41 = (const f4*)((cc1 == 0 ? u_reg : u_food) + (size_t)(bj0 + 1) * C);
    const f4* __restrict__ u04 = (const f4*)(u0  + (size_t)b * C);
    const f4* __restrict__ p4  = (const f4*)(pop + (size_t)b * C);

    float acc0 = 0.0f, acc1 = 0.0f;
    for (int c4 = t; c4 < C / 4; c4 += 256) {
        const f4 ov = u04[c4];
        const f4 pv = p4[c4];
        if (a0) {
            const f4 uv = __builtin_nontemporal_load(u40 + c4);
            acc0 += pv.x * uv.x * rcpf(ov.x + uv.x + EPSV);
            acc0 += pv.y * uv.y * rcpf(ov.y + uv.y + EPSV);
            acc0 += pv.z * uv.z * rcpf(ov.z + uv.z + EPSV);
            acc0 += pv.w * uv.w * rcpf(ov.w + uv.w + EPSV);
        }
        if (a1) {
            const f4 uv = __builtin_nontemporal_load(u41 + c4);
            acc1 += pv.x * uv.x * rcpf(ov.x + uv.x + EPSV);
            acc1 += pv.y * uv.y * rcpf(ov.y + uv.y + EPSV);
            acc1 += pv.z * uv.z * rcpf(ov.z + uv.z + EPSV);
            acc1 += pv.w * uv.w * rcpf(ov.w + uv.w + EPSV);
        }
    }

    __shared__ float red[2][4];
    const float w0 = waveReduceSum(acc0);
    const float w1 = waveReduceSum(acc1);
    if ((t & 63) == 0) { red[0][t >> 6] = w0; red[1][t >> 6] = w1; }
    __syncthreads();
    if (t < 2) {
        const int  bj  = bj0 + t;
        const int  cc  = (t == 0) ? cc0 : cc1;
        const bool act = cc < 2;
        const float s  = red[t][0] + red[t][1] + red[t][2] + red[t][3];
        const float revenue = (cc == 0 ? LAMBDA_G : LAMBDA_F) * s;   // 0 if inactive
        const float ddv = act ? (cc == 0 ? dd_reg[bj] : dd_food[bj]) : 0.0f;
        const float fx  = act ? fcp[bj] : 0.0f;
        const float adv = 0.11f * revenue - 3.5e-3f * ddv - fx;
        reward[bj] = fmaxf(adv, 0.0f) * 0.01f;
    }
}

// B*S blocks: exp-weighted partial context over a 40-row slab + partial sum(exp).
// reward in [0, ~9] so exp() needs no max-subtraction (softmax shift-invariant).
__global__ __launch_bounds__(256) void ctx_partial_kernel(
    const float* __restrict__ reward, const float* __restrict__ emb,
    float* __restrict__ partials, float* __restrict__ psum)
{
    const int blk = blockIdx.x;
    const int b = blk / S, s = blk % S;
    const int t = threadIdx.x;
    const int d4 = t & 31;       // which float4 along D (32*4 = 128)
    const int rg = t >> 5;       // row group 0..7

    const float* __restrict__ eb = emb + ((size_t)b * N + s * RPB) * D;
    const float* __restrict__ rv = reward + b * N + s * RPB;

    __shared__ float esum[RPB];

    f4 acc = {0.f, 0.f, 0.f, 0.f};
#pragma unroll
    for (int k = 0; k < RPT; ++k) {
        const int j = rg * RPT + k;
        const float w = __expf(rv[j]);
        if (d4 == 0) esum[j] = w;
        const f4 v = ((const f4*)(eb + (size_t)j * D))[d4];
        acc += v * w;
    }

    __shared__ float lds[8][D];
    *(f4*)&lds[rg][d4 * 4] = acc;
    __syncthreads();
    if (t < D) {
        float sum = 0.f;
#pragma unroll
        for (int g = 0; g < 8; ++g) sum += lds[g][t];
        partials[((size_t)b * S + s) * D + t] = sum;
    }
    if (t == 0) {
        float se = 0.f;
#pragma unroll
        for (int j = 0; j < RPB; ++j) se += esum[j];
        psum[b * S + s] = se;
    }
}

// 8 blocks: reduce S partials + sumexp -> ctx, then out = ctx @ W^T + bias
__global__ __launch_bounds__(128) void finalize_kernel(
    const float* __restrict__ partials, const float* __restrict__ psum,
    const float* __restrict__ Wm, const float* __restrict__ bias,
    float* __restrict__ out)
{
    const int b = blockIdx.x;
    const int t = threadIdx.x;

    __shared__ float ctx[D];
    float sum = 0.f, se = 0.f;
#pragma unroll 5
    for (int si = 0; si < S; ++si) {
        sum += partials[((size_t)b * S + si) * D + t];
        se  += psum[b * S + si];
    }
    ctx[t] = sum * rcpf(se);
    __syncthreads();

    const float* __restrict__ wr = Wm + t * D;
    float a = bias[t];
#pragma unroll 8
    for (int dd = 0; dd < D; ++dd) a += ctx[dd] * wr[dd];
    out[b * D + t] = a;
}

extern "C" void kernel_launch(void* const* d_in, const int* in_sizes, int n_in,
                              void* d_out, int out_size, void* d_ws, size_t ws_size,
                              hipStream_t stream) {
    const float* emb     = (const float*)d_in[0];   // [B,N,D]
    const int*   chosen  = (const int*)  d_in[1];   // [B,N]
    const float* u_reg   = (const float*)d_in[2];   // [B,N,C]
    const float* u_food  = (const float*)d_in[3];   // [B,N,C]
    const float* u0      = (const float*)d_in[4];   // [B,C]
    const float* pop     = (const float*)d_in[5];   // [B,C,1]
    const float* dd_reg  = (const float*)d_in[6];   // [B,N,1]
    const float* dd_food = (const float*)d_in[7];   // [B,N,1]
    const float* fcp     = (const float*)d_in[8];   // [B,1,N]
    const float* Wm      = (const float*)d_in[9];   // [D,D]
    const float* bias    = (const float*)d_in[10];  // [D]
    float* out = (float*)d_out;

    float* reward   = (float*)d_ws;                 // B*N
    float* partials = reward + B * N;               // B*S*D
    float* psum     = partials + B * S * D;         // B*S

    reward_pair_kernel<<<B * N / 2, 256, 0, stream>>>(u_reg, u_food, u0, pop, chosen,
                                                      dd_reg, dd_food, fcp, reward);
    ctx_partial_kernel<<<B * S, 256, 0, stream>>>(reward, emb, partials, psum);
    finalize_kernel<<<B, 128, 0, stream>>>(partials, psum, Wm, bias, out);
}